// Round 11
// baseline (64.981 us; speedup 1.0000x reference)
//
#include <hip/hip_runtime.h>

// DependencyGenerator, R11: bucketize + fused fill/scatter.
// Fill uses the proven 256x256 grid-stride float4 pattern. Stride window
// (256*256*4 floats) == ROWELEM, so block b writes floats [b*1024,(b+1)*1024)
// of EVERY row -> block b exclusively owns scatter targets with idx>>10==b.
// Pre-kernel buckets entries by owner into d_ws; fused kernel fills, drains
// its own stores (__syncthreads), then scatters its bucket (LDS hash,
// max-ordinal-wins = numpy last-duplicate-wins). Counters zeroed via
// hipMemsetAsync graph node each replay (deterministic).

#define SEQ_L   512
#define LM1     511
#define ROWELEM (SEQ_L * SEQ_L)       // 262144 floats per row
#define NT      256
#define BLOCKS  256                   // fill grid; owner = idx>>10 in [0,256)
#define CAP     512                   // bucket capacity (mean 255.5, sigma~16)
#define HSLOTS  1024

typedef float vfloat4 __attribute__((ext_vector_type(4)));

// ws layout: [0,1KB): u32 cnt[256]; [1KB, 1KB+256*CAP*8): uint2 buckets.
__global__ __launch_bounds__(NT) void bucketize_kernel(
    const int*   __restrict__ dep_i,
    const int*   __restrict__ dep_j,
    const int*   __restrict__ dep_type,
    const float* __restrict__ dep_emb,
    unsigned int* __restrict__ ws)
{
    const int row  = blockIdx.x;
    const int base = row * LM1;
    unsigned int* cnt = ws;
    uint2* buckets = reinterpret_cast<uint2*>(ws + 256);

    for (int k = threadIdx.x; k < LM1; k += NT) {
        const int idx = dep_i[base + k] * SEQ_L + dep_j[base + k];
        const float val = dep_emb[dep_type[base + k]];
        const unsigned owner = (unsigned)idx >> 10;
        // pack: k(9b)<<19 | row(9b)<<10 | idxlow(10b)  (all < 2^28)
        const unsigned pack = ((unsigned)k << 19) | ((unsigned)row << 10)
                            | ((unsigned)idx & 1023u);
        const unsigned pos = atomicAdd(&cnt[owner], 1u);
        buckets[owner * CAP + pos] = make_uint2(pack, __float_as_uint(val));
    }
}

__device__ __forceinline__ unsigned hash_key(unsigned key) {
    return (key * 2654435761u) >> 22;            // 10 bits
}

__global__ __launch_bounds__(NT) void fill_scatter_kernel(
    float* __restrict__ out,
    const unsigned int* __restrict__ ws,
    unsigned int n4)
{
    __shared__ int      h_key[HSLOTS];
    __shared__ unsigned h_pack[HSLOTS];

    const int b = blockIdx.x;
    const int t = threadIdx.x;

    for (int h = t; h < HSLOTS; h += NT) { h_key[h] = -1; h_pack[h] = 0; }

    // Fill: proven grid-stride pattern (window == one row).
    {
        const vfloat4 ones = {1.f, 1.f, 1.f, 1.f};
        vfloat4* o4 = reinterpret_cast<vfloat4*>(out);
        const unsigned stride = BLOCKS * NT;          // 65536 f4 = ROWELEM
        unsigned i = b * NT + t;
        #pragma unroll 4
        for (; i < n4; i += stride)
            o4[i] = ones;
    }

    // Drain this block's fill stores (vmcnt(0) + barrier). Our scatter
    // targets (idx>>10 == b) were filled exclusively by this block.
    __syncthreads();

    const unsigned n = ws[b];                         // bucket count
    const uint2* bucket = reinterpret_cast<const uint2*>(ws + 256) + b * CAP;

    // Insert: claim slot per key(row,idxlow); atomicMax of pack -> max k wins.
    for (unsigned e = t; e < n; e += NT) {
        const uint2 ent = bucket[e];
        const unsigned key = ent.x & 0x7FFFFu;        // row<<10 | idxlow
        unsigned h = hash_key(key);
        while (true) {
            int prev = atomicCAS(&h_key[h], -1, (int)key);
            if (prev == -1 || prev == (int)key) {
                atomicMax(&h_pack[h], ent.x);
                break;
            }
            h = (h + 1) & (HSLOTS - 1);
        }
    }
    __syncthreads();

    // Resolve + store winners.
    for (unsigned e = t; e < n; e += NT) {
        const uint2 ent = bucket[e];
        const unsigned key = ent.x & 0x7FFFFu;
        unsigned h = hash_key(key);
        while (h_key[h] != (int)key) h = (h + 1) & (HSLOTS - 1);
        if (h_pack[h] == ent.x) {
            const unsigned row    = (ent.x >> 10) & 0x1FFu;
            const unsigned idxlow = ent.x & 0x3FFu;
            out[(size_t)row * ROWELEM + ((size_t)b << 10) + idxlow] =
                __uint_as_float(ent.y);
        }
    }
}

extern "C" void kernel_launch(void* const* d_in, const int* in_sizes, int n_in,
                              void* d_out, int out_size, void* d_ws, size_t ws_size,
                              hipStream_t stream) {
    const int*   dep_i    = (const int*)  d_in[0];
    const int*   dep_j    = (const int*)  d_in[1];
    const int*   dep_type = (const int*)  d_in[2];
    // d_in[3] = seq_len scalar (512)
    const float* dep_emb  = (const float*)d_in[4];
    float*       out      = (float*)      d_out;
    unsigned int* ws      = (unsigned int*)d_ws;

    const int b = in_sizes[0] / LM1;                       // 128 rows
    const unsigned int n4 = (unsigned int)((size_t)b * ROWELEM / 4);

    // Zero bucket counters (graph memset node; deterministic each replay).
    hipMemsetAsync(ws, 0, 256 * sizeof(unsigned int), stream);
    bucketize_kernel<<<dim3(b), dim3(NT), 0, stream>>>(
        dep_i, dep_j, dep_type, dep_emb, ws);
    fill_scatter_kernel<<<dim3(BLOCKS), dim3(NT), 0, stream>>>(out, ws, n4);
}